// Round 3
// baseline (405.771 us; speedup 1.0000x reference)
//
#include <hip/hip_runtime.h>
#include <hip/hip_bf16.h>
#include <math.h>

typedef _Float16 f16;
typedef _Float16 f16x8 __attribute__((ext_vector_type(8)));
typedef _Float16 f16x4 __attribute__((ext_vector_type(4)));
typedef _Float16 f16x2 __attribute__((ext_vector_type(2)));
typedef float    f32x4 __attribute__((ext_vector_type(4)));

#define NN 1024      // nodes
#define EE 2048      // edges
#define DD 256       // hidden
#define EDH 128      // edge-MLP hidden
#define NT 33280     // 256*128 (f,k) + 256 root + 256 b2 columns
#define SCAP 16      // LDS-staged edges per node in agg

// ---------------- prep: embed (+bn stats) fused with edge-MLP ----------------

__global__ __launch_bounds__(256) void k_embed_hidden(const float* __restrict__ x,
    const float* __restrict__ lw, const float* __restrict__ lb,
    const float* __restrict__ ea, const float* __restrict__ w1, const float* __restrict__ b1,
    float* __restrict__ y, float* __restrict__ colsum, float* __restrict__ colsq,
    float* __restrict__ hid) {
  int bid = blockIdx.x, t = threadIdx.x;
  if (bid < NN) {                      // embed + batch-stat accumulate
    int n = bid;
    __shared__ float xr[38];
    if (t < 38) xr[t] = x[n*38 + t];
    __syncthreads();
    float s = lb[t];
    const float* w = lw + t*38;
    #pragma unroll
    for (int d = 0; d < 38; d++) s += xr[d] * w[d];
    y[n*DD + t] = s;
    atomicAdd(&colsum[t], s);
    atomicAdd(&colsq[t], s*s);
  } else {                             // edge MLP: sigmoid(ea @ w1^T + b1)
    int e = (bid - NN)*2 + (t >> 7);
    int k = t & 127;
    const float* a = ea + e*4;
    const float* w = w1 + k*4;
    float s = b1[k] + a[0]*w[0] + a[1]*w[1] + a[2]*w[2] + a[3]*w[3];
    hid[e*EDH + k] = 1.f / (1.f + expf(-s));
  }
}

// bn normalize -> xh f32, xc16 f16, Agru h-half f16
__global__ __launch_bounds__(256) void k_bnapply(const float* __restrict__ y,
    const float* __restrict__ colsum, const float* __restrict__ colsq,
    const float* __restrict__ g, const float* __restrict__ b,
    float* __restrict__ xh, f16* __restrict__ xc16, f16* __restrict__ Agru) {
  int i = blockIdx.x*256 + threadIdx.x;
  int c = i & 255, row = i >> 8;
  float mean = colsum[c] * (1.f/1024.f);
  float var  = colsq[c] * (1.f/1024.f) - mean*mean;
  float sc = g[c] / sqrtf(var + 1e-5f);
  float sh = b[c] - mean*sc;
  float v = y[i]*sc + sh;
  xh[i] = v;
  xc16[i] = (f16)v;
  Agru[(size_t)row*512 + 256 + c] = (f16)v;
}

// ---------------- CSR build ----------------

__global__ __launch_bounds__(256) void k_cnt(const int* __restrict__ dst, int* __restrict__ cnt) {
  int e = blockIdx.x*256 + threadIdx.x;
  atomicAdd(&cnt[dst[e]], 1);
}

__global__ __launch_bounds__(1024) void k_scan(const int* __restrict__ cnt,
    int* __restrict__ off, int* __restrict__ cursor, float* __restrict__ denom) {
  __shared__ int sc[1024];
  int t = threadIdx.x;
  int c = cnt[t];
  sc[t] = c; __syncthreads();
  for (int o = 1; o < 1024; o <<= 1) {
    int v = (t >= o) ? sc[t - o] : 0;
    __syncthreads();
    sc[t] += v;
    __syncthreads();
  }
  int ex = sc[t] - c;
  off[t] = ex; cursor[t] = ex;
  denom[t] = (float)(c > 1 ? c : 1);
}

__global__ __launch_bounds__(256) void k_fill(const int* __restrict__ dst,
    int* __restrict__ cursor, int* __restrict__ eord) {
  int e = blockIdx.x*256 + threadIdx.x;
  int p = atomicAdd(&cursor[dst[e]], 1);
  eord[p] = e;
}

// ---------------- BTb build: BTb[(f*128+k)*256 + d] = nn_w2[(d*256+f)*128 + k] ----------------
// LDS transpose, grid (256 f, 2 d-halves)

__global__ __launch_bounds__(256) void k_w2tr(const float* __restrict__ w2, f16* __restrict__ BTb) {
  __shared__ f16 ls[128][130];
  int f = blockIdx.x, dh = blockIdx.y, t = threadIdx.x;
  int dl = t >> 1, kh = (t & 1) * 64;          // thread reads row d_local, one k-half
  const float* src = w2 + ((size_t)(dh*128 + dl)*256 + f)*128 + kh;
  #pragma unroll
  for (int i = 0; i < 16; i++) {
    f32x4 v = *(const f32x4*)(src + i*4);
    f16x2 a = {(f16)v[0], (f16)v[1]};
    f16x2 b = {(f16)v[2], (f16)v[3]};
    *(f16x2*)(&ls[dl][kh + i*4])     = a;
    *(f16x2*)(&ls[dl][kh + i*4 + 2]) = b;
  }
  __syncthreads();
  int k = t >> 1, dh2 = (t & 1) * 64;          // thread writes row k, one d-half
  f16* dst = BTb + ((size_t)f*128 + k)*256 + dh*128 + dh2;
  #pragma unroll
  for (int g = 0; g < 8; g++) {
    f16x8 pk;
    #pragma unroll
    for (int q = 0; q < 8; q++) pk[q] = ls[dh2 + g*8 + q][k];
    *(f16x8*)(dst + g*8) = pk;
  }
}

// root rows (32768+f): root_w[f*256+d] linear cast; b2 rows (33024+f): transpose nn_b2[d*256+f]
__global__ __launch_bounds__(256) void k_auxB(const float* __restrict__ rw,
    const float* __restrict__ nb2, f16* __restrict__ BTb) {
  int bid = blockIdx.x, t = threadIdx.x;
  if (bid < 64) {                              // root: 65536 f32, linear
    int i = bid*256 + t;
    f32x4 v = *(const f32x4*)(rw + (size_t)i*4);
    f16x4 r; r[0]=(f16)v[0]; r[1]=(f16)v[1]; r[2]=(f16)v[2]; r[3]=(f16)v[3];
    *(f16x4*)(BTb + (size_t)32768*256 + (size_t)i*4) = r;
  } else {                                     // b2 transpose, 64x64 tiles
    __shared__ float ls[64][65];
    int fb = bid - 64;                         // 0..3
    for (int db = 0; db < 4; db++) {
      int r = t >> 2, cs = (t & 3) * 16;
      const float* s = nb2 + (size_t)(db*64 + r)*256 + fb*64 + cs;
      #pragma unroll
      for (int i = 0; i < 16; i += 4) {
        f32x4 v = *(const f32x4*)(s + i);
        ls[r][cs+i] = v[0]; ls[r][cs+i+1] = v[1]; ls[r][cs+i+2] = v[2]; ls[r][cs+i+3] = v[3];
      }
      __syncthreads();
      int fl = t >> 2, ds2 = (t & 3) * 16;
      f16x8 p0, p1;
      #pragma unroll
      for (int q = 0; q < 8; q++) { p0[q] = (f16)ls[ds2+q][fl]; p1[q] = (f16)ls[ds2+8+q][fl]; }
      f16* d = BTb + (size_t)(33024 + fb*64 + fl)*256 + db*64 + ds2;
      *(f16x8*)(d)     = p0;
      *(f16x8*)(d + 8) = p1;
      __syncthreads();
    }
  }
}

// one kernel, 4 cast segments (gru_wih, gru_whh, mlp_w1, mlp_w2)
__global__ __launch_bounds__(256) void k_castall(const float* __restrict__ s0, f16* __restrict__ d0,
    const float* __restrict__ s1, f16* __restrict__ d1,
    const float* __restrict__ s2, f16* __restrict__ d2,
    const float* __restrict__ s3, f16* __restrict__ d3) {
  int bid = blockIdx.x, t = threadIdx.x;
  const float* src; f16* dst; int i;
  if      (bid < 192)  { src = s0; dst = d0; i = bid*256 + t; }
  else if (bid < 384)  { src = s1; dst = d1; i = (bid-192)*256 + t; }
  else if (bid < 1024) { src = s2; dst = d2; i = (bid-384)*256 + t; }
  else                 { src = s3; dst = d3; i = (bid-1024)*256 + t; }
  f32x4 v = ((const f32x4*)src)[i];
  f16x4 r; r[0]=(f16)v[0]; r[1]=(f16)v[1]; r[2]=(f16)v[2]; r[3]=(f16)v[3];
  ((f16x4*)dst)[i] = r;
}

// ---------------- GEMM1: T[1024][33280] = xc16[1024][256] @ BTb[33280][256]^T ----------------
// 128x128 tile, K=256, BK=32, reg-staged pad-40 LDS, f16 output

__global__ __launch_bounds__(256) void k_gemm1(const f16* __restrict__ A,
    const f16* __restrict__ BT, f16* __restrict__ T) {
  __shared__ __align__(16) f16 As[128*40];
  __shared__ __align__(16) f16 Bs[128*40];
  int t = threadIdx.x;
  int m0 = blockIdx.x*128, n0 = blockIdx.y*128;
  int lane = t & 63, wv = t >> 6, wm = wv >> 1, wn = wv & 1;
  int lr = lane & 15, lk = (lane >> 4) * 8;
  int arow = t >> 2, aseg = (t & 3) * 8;
  f32x4 acc[4][4] = {};
  for (int k0 = 0; k0 < 256; k0 += 32) {
    __syncthreads();
    #pragma unroll
    for (int p = 0; p < 2; p++) {
      f16x8 va = *(const f16x8*)(A  + (size_t)(m0 + p*64 + arow)*256 + k0 + aseg);
      *(f16x8*)(&As[(p*64 + arow)*40 + aseg]) = va;
      f16x8 vb = *(const f16x8*)(BT + (size_t)(n0 + p*64 + arow)*256 + k0 + aseg);
      *(f16x8*)(&Bs[(p*64 + arow)*40 + aseg]) = vb;
    }
    __syncthreads();
    f16x8 af[4], bf[4];
    #pragma unroll
    for (int i = 0; i < 4; i++) af[i] = *(const f16x8*)(&As[(wm*64 + i*16 + lr)*40 + lk]);
    #pragma unroll
    for (int j = 0; j < 4; j++) bf[j] = *(const f16x8*)(&Bs[(wn*64 + j*16 + lr)*40 + lk]);
    #pragma unroll
    for (int i = 0; i < 4; i++)
      #pragma unroll
      for (int j = 0; j < 4; j++)
        acc[i][j] = __builtin_amdgcn_mfma_f32_16x16x32_f16(af[i], bf[j], acc[i][j], 0, 0, 0);
  }
  #pragma unroll
  for (int i = 0; i < 4; i++)
    #pragma unroll
    for (int j = 0; j < 4; j++)
      #pragma unroll
      for (int v = 0; v < 4; v++) {
        int r = m0 + wm*64 + i*16 + (lane >> 4)*4 + v;
        int c = n0 + wn*64 + j*16 + lr;
        T[(size_t)r*NT + c] = (f16)acc[i][j][v];
      }
}

// ---------------- agg: m[n,f] = relu( (Σ_e Σ_k h[e,k]T[src,(f,k)] + T[src,b2_f]) /denom
//                                      + T[n,root_f] + conv_b[f] ) ----------------

__global__ __launch_bounds__(256) void k_agg(const f16* __restrict__ T,
    const float* __restrict__ hid, const int* __restrict__ srcArr,
    const int* __restrict__ cnt, const int* __restrict__ offn, const int* __restrict__ eord,
    const float* __restrict__ denomB, const float* __restrict__ cb, f16* __restrict__ Agru) {
  int n = blockIdx.x, t = threadIdx.x;      // t = f
  __shared__ float hs[SCAP][EDH];
  __shared__ int ss[SCAP];
  int deg = cnt[n], o = offn[n];
  int stg = deg < SCAP ? deg : SCAP;
  for (int idx = t; idx < stg*EDH; idx += 256) {
    int j = idx >> 7, k = idx & 127;
    hs[j][k] = hid[eord[o+j]*EDH + k];
  }
  if (t < stg) ss[t] = srcArr[eord[o+t]];
  __syncthreads();
  float acc = 0.f;
  for (int j = 0; j < stg; j++) {
    const f16* Tr = T + (size_t)ss[j]*NT;
    float s = (float)Tr[33024 + t];          // b2 term
    const f16* Trf = Tr + t*128;
    #pragma unroll
    for (int c8 = 0; c8 < 16; c8++) {
      f16x8 v = *(const f16x8*)(Trf + c8*8);
      #pragma unroll
      for (int q = 0; q < 8; q++) s += hs[j][c8*8 + q] * (float)v[q];
    }
    acc += s;
  }
  for (int j = SCAP; j < deg; j++) {         // rare overflow path
    int e = eord[o+j];
    const f16* Tr = T + (size_t)srcArr[e]*NT;
    float s = (float)Tr[33024 + t];
    const f16* Trf = Tr + t*128;
    for (int c8 = 0; c8 < 16; c8++) {
      f16x8 v = *(const f16x8*)(Trf + c8*8);
      for (int q = 0; q < 8; q++) s += hid[e*EDH + c8*8 + q] * (float)v[q];
    }
    acc += s;
  }
  float m = acc / denomB[n] + (float)T[(size_t)n*NT + 32768 + t] + cb[t];
  m = fmaxf(m, 0.f);
  Agru[(size_t)n*512 + t] = (f16)m;
}

// ---------------- small GEMM: 64x128 tile. MODE 1: f32 store; MODE 3: bias+relu f16 ----------------

template<int MODE>
__global__ __launch_bounds__(256) void k_gemm_sm(const f16* __restrict__ A,
    const f16* __restrict__ BT, float* __restrict__ C, f16* __restrict__ Ch,
    const float* __restrict__ bias, int K, int lda, int ldb, int N,
    int bsA, int bsB, int bsC, int bsBias) {
  __shared__ __align__(16) f16 As[64*40];
  __shared__ __align__(16) f16 Bs[128*40];
  int t = threadIdx.x;
  int m0 = blockIdx.x*64, n0 = blockIdx.y*128, z = blockIdx.z;
  A  += (size_t)z * bsA;
  BT += (size_t)z * bsB;
  if constexpr (MODE == 1) C += (size_t)z * bsC;
  else { Ch += (size_t)z * bsC; bias += (size_t)z * bsBias; }
  int lane = t & 63, wv = t >> 6, wm = wv >> 1, wn = wv & 1;
  int lr = lane & 15, lk = (lane >> 4) * 8;
  int arow = t >> 2, aseg = (t & 3) * 8;
  f32x4 acc[2][4] = {};
  for (int k0 = 0; k0 < K; k0 += 32) {
    __syncthreads();
    *(f16x8*)(&As[arow*40 + aseg]) = *(const f16x8*)(A + (size_t)(m0 + arow)*lda + k0 + aseg);
    *(f16x8*)(&Bs[arow*40 + aseg]) = *(const f16x8*)(BT + (size_t)(n0 + arow)*ldb + k0 + aseg);
    *(f16x8*)(&Bs[(64+arow)*40 + aseg]) = *(const f16x8*)(BT + (size_t)(n0 + 64 + arow)*ldb + k0 + aseg);
    __syncthreads();
    f16x8 af[2], bf[4];
    #pragma unroll
    for (int i = 0; i < 2; i++) af[i] = *(const f16x8*)(&As[(wm*32 + i*16 + lr)*40 + lk]);
    #pragma unroll
    for (int j = 0; j < 4; j++) bf[j] = *(const f16x8*)(&Bs[(wn*64 + j*16 + lr)*40 + lk]);
    #pragma unroll
    for (int i = 0; i < 2; i++)
      #pragma unroll
      for (int j = 0; j < 4; j++)
        acc[i][j] = __builtin_amdgcn_mfma_f32_16x16x32_f16(af[i], bf[j], acc[i][j], 0, 0, 0);
  }
  #pragma unroll
  for (int i = 0; i < 2; i++)
    #pragma unroll
    for (int j = 0; j < 4; j++)
      #pragma unroll
      for (int v = 0; v < 4; v++) {
        int r = m0 + wm*32 + i*16 + (lane >> 4)*4 + v;
        int c = n0 + wn*64 + j*16 + lr;
        float val = acc[i][j][v];
        if constexpr (MODE == 1) {
          C[(size_t)r*N + c] = val;
        } else {
          val += bias[c];
          val = fmaxf(val, 0.f);
          Ch[(size_t)r*N + c] = (f16)val;
        }
      }
}

// ---------------- GRU gates ----------------

__global__ __launch_bounds__(256) void k_gate(const float* __restrict__ gi,
    const float* __restrict__ gh, const float* __restrict__ bih, const float* __restrict__ bhh,
    const float* __restrict__ hOld, float* __restrict__ hNew, f16* __restrict__ xc16,
    f16* __restrict__ Agru) {
  int i = blockIdx.x*256 + threadIdx.x;
  int row = i >> 8, c = i & 255;
  const float* gir = gi + (size_t)row*768;
  const float* ghr = gh + (size_t)row*768;
  float ir  = gir[c]     + bih[c],     hr = ghr[c]     + bhh[c];
  float iz  = gir[256+c] + bih[256+c], hz = ghr[256+c] + bhh[256+c];
  float inn = gir[512+c] + bih[512+c], hn = ghr[512+c] + bhh[512+c];
  float r  = 1.f / (1.f + expf(-(ir + hr)));
  float zz = 1.f / (1.f + expf(-(iz + hz)));
  float nn = tanhf(inn + r*hn);
  float hv = (1.f - zz)*nn + zz*hOld[i];
  hNew[i] = hv;
  xc16[i] = (f16)hv;
  Agru[(size_t)row*512 + 256 + c] = (f16)hv;
}

// ---------------- head tail ----------------

__global__ __launch_bounds__(256) void k_mix(const f16* __restrict__ h2,
    const float* __restrict__ w3, const float* __restrict__ b3, float* __restrict__ mix) {
  int b = blockIdx.x, t = threadIdx.x;
  int wv = t >> 6, lane = t & 63;
  int rid = b*4 + wv;
  int m = rid >> 10, row = rid & 1023;
  const f16* hr = h2 + (size_t)(m*1024 + row)*DD;
  const float* w = w3 + m*DD;
  float s = 0.f;
  #pragma unroll
  for (int q = 0; q < 4; q++) { int d = lane + q*64; s += (float)hr[d] * w[d]; }
  #pragma unroll
  for (int o = 32; o; o >>= 1) s += __shfl_down(s, o, 64);
  if (lane == 0) mix[m*1024 + row] = s + b3[m];
}

__global__ __launch_bounds__(256) void k_out(const float* __restrict__ mix, float* __restrict__ out) {
  int i = blockIdx.x*256 + threadIdx.x;
  float v[10]; float mu = 0.f;
  #pragma unroll
  for (int m = 0; m < 10; m++) { v[m] = mix[m*1024 + i]; mu += v[m]; }
  mu *= 0.1f;
  float var = 0.f;
  #pragma unroll
  for (int m = 0; m < 10; m++) { float d = v[m] - mu; var += d*d; }
  var *= (1.f/9.f);
  out[i] = mu;
  out[1024 + i] = sqrtf(var + 1e-5f);
}

// ---------------- launch ----------------

extern "C" void kernel_launch(void* const* d_in, const int* in_sizes, int n_in,
                              void* d_out, int out_size, void* d_ws, size_t ws_size,
                              hipStream_t stream) {
  const float* x         = (const float*)d_in[0];
  const float* edge_attr = (const float*)d_in[1];
  const int*   edge_idx  = (const int*)  d_in[2];
  const float* lin_w     = (const float*)d_in[3];
  const float* lin_b     = (const float*)d_in[4];
  const float* bn_g      = (const float*)d_in[5];
  const float* bn_b      = (const float*)d_in[6];
  const float* nn_w1     = (const float*)d_in[7];
  const float* nn_b1     = (const float*)d_in[8];
  const float* nn_w2     = (const float*)d_in[9];
  const float* nn_b2     = (const float*)d_in[10];
  const float* root_w    = (const float*)d_in[11];
  const float* conv_b    = (const float*)d_in[12];
  const float* gru_wih   = (const float*)d_in[13];
  const float* gru_whh   = (const float*)d_in[14];
  const float* gru_bih   = (const float*)d_in[15];
  const float* gru_bhh   = (const float*)d_in[16];
  const float* mlp_w1    = (const float*)d_in[17];
  const float* mlp_b1    = (const float*)d_in[18];
  const float* mlp_w2    = (const float*)d_in[19];
  const float* mlp_b2    = (const float*)d_in[20];
  const float* mlp_w3    = (const float*)d_in[21];
  const float* mlp_b3    = (const float*)d_in[22];
  float* out = (float*)d_out;

  char* w = (char*)d_ws;
  size_t o = 0;
  auto nxt = [&](size_t b) -> size_t { size_t r = o; o += (b + 255) & ~(size_t)255; return r; };
  float* y      = (float*)(w + nxt(1048576));
  float* colsum = (float*)(w + nxt(1024));
  float* colsq  = (float*)(w + nxt(1024));
  float* xh     = (float*)(w + nxt(1048576));
  float* h      = (float*)(w + nxt(1048576));
  f16*   xc16   = (f16*)  (w + nxt(524288));
  float* hid    = (float*)(w + nxt(1048576));
  int*   cnt    = (int*)  (w + nxt(4096));
  int*   offn   = (int*)  (w + nxt(4096));
  int*   cursor = (int*)  (w + nxt(4096));
  float* denomB = (float*)(w + nxt(4096));
  int*   eord   = (int*)  (w + nxt(8192));
  f16*   BTb    = (f16*)  (w + nxt((size_t)NT*256*2));          // 17.0 MB
  f16*   T      = (f16*)  (w + nxt((size_t)1024*NT*2));         // 68.2 MB
  f16*   Agru   = (f16*)  (w + nxt(1048576));                   // [1024][512] = [m | h]
  float* G      = (float*)(w + nxt((size_t)2*1024*768*4));      // gi, gh
  f16*   Wb     = (f16*)  (w + nxt(786432));                    // [2][768][256]
  f16*   w1T    = (f16*)  (w + nxt(1310720));
  f16*   w2T    = (f16*)  (w + nxt(1310720));
  f16*   h1     = (f16*)  (w + nxt(5242880));
  f16*   h2     = (f16*)  (w + nxt(5242880));
  float* mixb   = (float*)(w + nxt(40960));
  if (o > ws_size) return;

  hipMemsetAsync(colsum, 0, 2048, stream);   // colsum + colsq contiguous
  hipMemsetAsync(cnt, 0, 4096, stream);

  k_embed_hidden<<<2048, 256, 0, stream>>>(x, lin_w, lin_b, edge_attr, nn_w1, nn_b1,
                                           y, colsum, colsq, hid);
  k_bnapply<<<1024, 256, 0, stream>>>(y, colsum, colsq, bn_g, bn_b, xh, xc16, Agru);
  k_cnt    <<<8, 256, 0, stream>>>(edge_idx + EE, cnt);
  k_scan   <<<1, 1024, 0, stream>>>(cnt, offn, cursor, denomB);
  k_fill   <<<8, 256, 0, stream>>>(edge_idx + EE, cursor, eord);
  k_w2tr   <<<dim3(256, 2), 256, 0, stream>>>(nn_w2, BTb);
  k_auxB   <<<68, 256, 0, stream>>>(root_w, nn_b2, BTb);
  k_castall<<<1664, 256, 0, stream>>>(gru_wih, Wb, gru_whh, Wb + 196608,
                                      mlp_w1, w1T, mlp_w2, w2T);

  for (int it = 0; it < 3; it++) {
    const float* hOld = (it == 0) ? xh : h;
    k_gemm1<<<dim3(8, 260), 256, 0, stream>>>(xc16, BTb, T);
    k_agg  <<<1024, 256, 0, stream>>>(T, hid, edge_idx, cnt, offn, eord, denomB, conv_b, Agru);
    k_gemm_sm<1><<<dim3(16, 6, 2), 256, 0, stream>>>(Agru, Wb, G,
        nullptr, nullptr, 256, 512, 256, 768, 256, 196608, 786432, 0);
    k_gate<<<1024, 256, 0, stream>>>(G, G + 786432, gru_bih, gru_bhh, hOld, h, xc16, Agru);
  }

  k_gemm_sm<3><<<dim3(16, 2, 10), 256, 0, stream>>>(Agru + 256, w1T, nullptr, h1, mlp_b1,
      256, 512, 256, 256, 0, 65536, 262144, 256);
  k_gemm_sm<3><<<dim3(16, 2, 10), 256, 0, stream>>>(h1, w2T, nullptr, h2, mlp_b2,
      256, 256, 256, 256, 262144, 65536, 262144, 256);
  k_mix<<<2560, 256, 0, stream>>>(h2, mlp_w3, mlp_b3, mixb);
  k_out<<<4, 256, 0, stream>>>(mixb, out);
}

// Round 4
// 301.526 us; speedup vs baseline: 1.3457x; 1.3457x over previous
//
#include <hip/hip_runtime.h>
#include <hip/hip_bf16.h>
#include <math.h>

typedef _Float16 f16;
typedef _Float16 f16x8 __attribute__((ext_vector_type(8)));
typedef _Float16 f16x4 __attribute__((ext_vector_type(4)));
typedef _Float16 f16x2 __attribute__((ext_vector_type(2)));
typedef float    f32x4 __attribute__((ext_vector_type(4)));

#define NN 1024      // nodes
#define EE 2048      // edges
#define DD 256       // hidden
#define EDH 128      // edge-MLP hidden
#define NT 33280     // 256*128 (f,k) + 256 root + 256 b2 columns
#define SCAP 16      // LDS-staged edges per node in msg

// ---------------- prep: embed (+bn stats) fused with edge-MLP ----------------

__global__ __launch_bounds__(256) void k_embed_hidden(const float* __restrict__ x,
    const float* __restrict__ lw, const float* __restrict__ lb,
    const float* __restrict__ ea, const float* __restrict__ w1, const float* __restrict__ b1,
    float* __restrict__ y, float* __restrict__ colsum, float* __restrict__ colsq,
    float* __restrict__ hid) {
  int bid = blockIdx.x, t = threadIdx.x;
  if (bid < NN) {                      // embed + batch-stat accumulate
    int n = bid;
    __shared__ float xr[38];
    if (t < 38) xr[t] = x[n*38 + t];
    __syncthreads();
    float s = lb[t];
    const float* w = lw + t*38;
    #pragma unroll
    for (int d = 0; d < 38; d++) s += xr[d] * w[d];
    y[n*DD + t] = s;
    atomicAdd(&colsum[t], s);
    atomicAdd(&colsq[t], s*s);
  } else {                             // edge MLP: sigmoid(ea @ w1^T + b1)
    int e = (bid - NN)*2 + (t >> 7);
    int k = t & 127;
    const float* a = ea + e*4;
    const float* w = w1 + k*4;
    float s = b1[k] + a[0]*w[0] + a[1]*w[1] + a[2]*w[2] + a[3]*w[3];
    hid[e*EDH + k] = 1.f / (1.f + expf(-s));
  }
}

// bn normalize -> xh f32, xc16 f16, Agru h-half f16
__global__ __launch_bounds__(256) void k_bnapply(const float* __restrict__ y,
    const float* __restrict__ colsum, const float* __restrict__ colsq,
    const float* __restrict__ g, const float* __restrict__ b,
    float* __restrict__ xh, f16* __restrict__ xc16, f16* __restrict__ Agru) {
  int i = blockIdx.x*256 + threadIdx.x;
  int c = i & 255, row = i >> 8;
  float mean = colsum[c] * (1.f/1024.f);
  float var  = colsq[c] * (1.f/1024.f) - mean*mean;
  float sc = g[c] / sqrtf(var + 1e-5f);
  float sh = b[c] - mean*sc;
  float v = y[i]*sc + sh;
  xh[i] = v;
  xc16[i] = (f16)v;
  Agru[(size_t)row*512 + 256 + c] = (f16)v;
}

// ---------------- dual CSR build (dst in slots [0,1024), src in [1024,2048)) ----------------

__global__ __launch_bounds__(256) void k_cnt2(const int* __restrict__ ei, int* __restrict__ cntAll) {
  int bid = blockIdx.x, t = threadIdx.x;
  int e = (bid & 7)*256 + t;
  if (bid < 8) atomicAdd(&cntAll[ei[EE + e]], 1);          // dst
  else         atomicAdd(&cntAll[1024 + ei[e]], 1);        // src
}

__global__ __launch_bounds__(1024) void k_scan2(const int* __restrict__ cntAll,
    int* __restrict__ offAll, int* __restrict__ curAll, float* __restrict__ denom) {
  __shared__ int sc[1024];
  int b = blockIdx.x, t = threadIdx.x;
  int base = b*1024;
  int c = cntAll[base + t];
  sc[t] = c; __syncthreads();
  for (int o = 1; o < 1024; o <<= 1) {
    int v = (t >= o) ? sc[t - o] : 0;
    __syncthreads();
    sc[t] += v;
    __syncthreads();
  }
  int ex = sc[t] - c;
  offAll[base + t] = ex; curAll[base + t] = ex;
  if (b == 0) denom[t] = (float)(c > 1 ? c : 1);
}

__global__ __launch_bounds__(256) void k_fill2(const int* __restrict__ ei,
    int* __restrict__ curAll, int* __restrict__ eordD, int* __restrict__ eordS,
    int* __restrict__ posArr) {
  int bid = blockIdx.x, t = threadIdx.x;
  int e = (bid & 7)*256 + t;
  if (bid < 8) {
    int p = atomicAdd(&curAll[ei[EE + e]], 1);
    eordD[p] = e; posArr[e] = p;
  } else {
    int p = atomicAdd(&curAll[1024 + ei[e]], 1);
    eordS[p] = e;
  }
}

// ---------------- BTb build: BTb[(f*128+k)*256 + d] = nn_w2[(d*256+f)*128 + k] ----------------

__global__ __launch_bounds__(256) void k_w2tr(const float* __restrict__ w2, f16* __restrict__ BTb) {
  __shared__ f16 ls[128][130];
  int f = blockIdx.x, dh = blockIdx.y, t = threadIdx.x;
  int dl = t >> 1, kh = (t & 1) * 64;
  const float* src = w2 + ((size_t)(dh*128 + dl)*256 + f)*128 + kh;
  #pragma unroll
  for (int i = 0; i < 16; i++) {
    f32x4 v = *(const f32x4*)(src + i*4);
    f16x2 a = {(f16)v[0], (f16)v[1]};
    f16x2 b = {(f16)v[2], (f16)v[3]};
    *(f16x2*)(&ls[dl][kh + i*4])     = a;
    *(f16x2*)(&ls[dl][kh + i*4 + 2]) = b;
  }
  __syncthreads();
  int k = t >> 1, dh2 = (t & 1) * 64;
  f16* dst = BTb + ((size_t)f*128 + k)*256 + dh*128 + dh2;
  #pragma unroll
  for (int g = 0; g < 8; g++) {
    f16x8 pk;
    #pragma unroll
    for (int q = 0; q < 8; q++) pk[q] = ls[dh2 + g*8 + q][k];
    *(f16x8*)(dst + g*8) = pk;
  }
}

// root rows (32768+f): root_w linear; b2 rows (33024+f): transpose nn_b2[d*256+f]
__global__ __launch_bounds__(256) void k_auxB(const float* __restrict__ rw,
    const float* __restrict__ nb2, f16* __restrict__ BTb) {
  int bid = blockIdx.x, t = threadIdx.x;
  if (bid < 64) {
    int i = bid*256 + t;
    f32x4 v = *(const f32x4*)(rw + (size_t)i*4);
    f16x4 r; r[0]=(f16)v[0]; r[1]=(f16)v[1]; r[2]=(f16)v[2]; r[3]=(f16)v[3];
    *(f16x4*)(BTb + (size_t)32768*256 + (size_t)i*4) = r;
  } else {
    __shared__ float ls[64][65];
    int fb = bid - 64;
    for (int db = 0; db < 4; db++) {
      int r = t >> 2, cs = (t & 3) * 16;
      const float* s = nb2 + (size_t)(db*64 + r)*256 + fb*64 + cs;
      #pragma unroll
      for (int i = 0; i < 16; i += 4) {
        f32x4 v = *(const f32x4*)(s + i);
        ls[r][cs+i] = v[0]; ls[r][cs+i+1] = v[1]; ls[r][cs+i+2] = v[2]; ls[r][cs+i+3] = v[3];
      }
      __syncthreads();
      int fl = t >> 2, ds2 = (t & 3) * 16;
      f16x8 p0, p1;
      #pragma unroll
      for (int q = 0; q < 8; q++) { p0[q] = (f16)ls[ds2+q][fl]; p1[q] = (f16)ls[ds2+8+q][fl]; }
      f16* d = BTb + (size_t)(33024 + fb*64 + fl)*256 + db*64 + ds2;
      *(f16x8*)(d)     = p0;
      *(f16x8*)(d + 8) = p1;
      __syncthreads();
    }
  }
}

__global__ __launch_bounds__(256) void k_castall(const float* __restrict__ s0, f16* __restrict__ d0,
    const float* __restrict__ s1, f16* __restrict__ d1,
    const float* __restrict__ s2, f16* __restrict__ d2,
    const float* __restrict__ s3, f16* __restrict__ d3) {
  int bid = blockIdx.x, t = threadIdx.x;
  const float* src; f16* dst; int i;
  if      (bid < 192)  { src = s0; dst = d0; i = bid*256 + t; }
  else if (bid < 384)  { src = s1; dst = d1; i = (bid-192)*256 + t; }
  else if (bid < 1024) { src = s2; dst = d2; i = (bid-384)*256 + t; }
  else                 { src = s3; dst = d3; i = (bid-1024)*256 + t; }
  f32x4 v = ((const f32x4*)src)[i];
  f16x4 r; r[0]=(f16)v[0]; r[1]=(f16)v[1]; r[2]=(f16)v[2]; r[3]=(f16)v[3];
  ((f16x4*)dst)[i] = r;
}

// ---------------- GEMM1: T[1024][33280] = xc16 @ BTb^T, XCD-grouped grid ----------------
// raw -> (xcd c, panel p, m): all 8 m-blocks of a B-panel land on one XCD.

__global__ __launch_bounds__(256) void k_gemm1(const f16* __restrict__ A,
    const f16* __restrict__ BT, f16* __restrict__ T) {
  __shared__ __align__(16) f16 As[128*40];
  __shared__ __align__(16) f16 Bs[128*40];
  int raw = blockIdx.x;
  int c = raw & 7, rank = raw >> 3;
  int p = c*33 + (rank >> 3), m = rank & 7;
  if (p >= 260) return;
  int m0 = m*128, n0 = p*128;
  int t = threadIdx.x;
  int lane = t & 63, wv = t >> 6, wm = wv >> 1, wn = wv & 1;
  int lr = lane & 15, lk = (lane >> 4) * 8;
  int arow = t >> 2, aseg = (t & 3) * 8;
  f32x4 acc[4][4] = {};
  for (int k0 = 0; k0 < 256; k0 += 32) {
    __syncthreads();
    #pragma unroll
    for (int q = 0; q < 2; q++) {
      f16x8 va = *(const f16x8*)(A  + (size_t)(m0 + q*64 + arow)*256 + k0 + aseg);
      *(f16x8*)(&As[(q*64 + arow)*40 + aseg]) = va;
      f16x8 vb = *(const f16x8*)(BT + (size_t)(n0 + q*64 + arow)*256 + k0 + aseg);
      *(f16x8*)(&Bs[(q*64 + arow)*40 + aseg]) = vb;
    }
    __syncthreads();
    f16x8 af[4], bf[4];
    #pragma unroll
    for (int i = 0; i < 4; i++) af[i] = *(const f16x8*)(&As[(wm*64 + i*16 + lr)*40 + lk]);
    #pragma unroll
    for (int j = 0; j < 4; j++) bf[j] = *(const f16x8*)(&Bs[(wn*64 + j*16 + lr)*40 + lk]);
    #pragma unroll
    for (int i = 0; i < 4; i++)
      #pragma unroll
      for (int j = 0; j < 4; j++)
        acc[i][j] = __builtin_amdgcn_mfma_f32_16x16x32_f16(af[i], bf[j], acc[i][j], 0, 0, 0);
  }
  #pragma unroll
  for (int i = 0; i < 4; i++)
    #pragma unroll
    for (int j = 0; j < 4; j++)
      #pragma unroll
      for (int v = 0; v < 4; v++) {
        int r = m0 + wm*64 + i*16 + (lane >> 4)*4 + v;
        int cc = n0 + wn*64 + j*16 + lr;
        T[(size_t)r*NT + cc] = (f16)acc[i][j][v];
      }
}

// ---------------- msg: per SRC node, T-row in regs, one msg per out-edge ----------------
// msg[e,f] = Sigma_k h[e,k] T[src,(f,k)] + T[src,b2_f]  -> msgbuf[pos(e)][f]

__global__ __launch_bounds__(256) void k_msg(const f16* __restrict__ T,
    const float* __restrict__ hid, const int* __restrict__ cntAll,
    const int* __restrict__ offAll, const int* __restrict__ eordS,
    const int* __restrict__ posArr, float* __restrict__ msgbuf) {
  int n = blockIdx.x, t = threadIdx.x;      // t = f
  int deg = cntAll[1024 + n];
  if (deg == 0) return;
  int o = offAll[1024 + n];
  __shared__ float hs[SCAP][EDH];
  __shared__ int es[SCAP];
  int stg = deg < SCAP ? deg : SCAP;
  for (int idx = t; idx < stg*EDH; idx += 256) {
    int j = idx >> 7, k = idx & 127;
    hs[j][k] = hid[eordS[o+j]*EDH + k];
  }
  if (t < stg) es[t] = eordS[o+t];
  __syncthreads();
  const f16* Tr = T + (size_t)n*NT + t*128;
  f16x8 tv[16];
  #pragma unroll
  for (int i = 0; i < 16; i++) tv[i] = *(const f16x8*)(Tr + i*8);
  float b2v = (float)T[(size_t)n*NT + 33024 + t];
  for (int j = 0; j < deg; j++) {
    float s = b2v;
    if (j < SCAP) {
      #pragma unroll
      for (int i = 0; i < 16; i++)
        #pragma unroll
        for (int q = 0; q < 8; q++) s += hs[j][i*8+q] * (float)tv[i][q];
      msgbuf[(size_t)posArr[es[j]]*256 + t] = s;
    } else {                               // vanishingly rare out-deg > SCAP
      int e = eordS[o+j];
      for (int i = 0; i < 16; i++)
        for (int q = 0; q < 8; q++) s += hid[e*EDH + i*8+q] * (float)tv[i][q];
      msgbuf[(size_t)posArr[e]*256 + t] = s;
    }
  }
}

// ---------------- fin: segment-sum msgbuf (dst-contiguous), /denom, +root+bias, relu ----------------

__global__ __launch_bounds__(256) void k_fin(const float* __restrict__ msgbuf,
    const int* __restrict__ cntAll, const int* __restrict__ offAll,
    const float* __restrict__ denomB, const f16* __restrict__ T,
    const float* __restrict__ cb, f16* __restrict__ Agru) {
  int n = blockIdx.x, t = threadIdx.x;
  int deg = cntAll[n], o = offAll[n];
  float s = 0.f;
  for (int j = 0; j < deg; j++) s += msgbuf[(size_t)(o+j)*256 + t];
  float m = s / denomB[n] + (float)T[(size_t)n*NT + 32768 + t] + cb[t];
  Agru[(size_t)n*512 + t] = (f16)fmaxf(m, 0.f);
}

// ---------------- small GEMM: 64x128 tile. MODE 1: f32 store; MODE 3: bias+relu f16 ----------------

template<int MODE>
__global__ __launch_bounds__(256) void k_gemm_sm(const f16* __restrict__ A,
    const f16* __restrict__ BT, float* __restrict__ C, f16* __restrict__ Ch,
    const float* __restrict__ bias, int K, int lda, int ldb, int N,
    int bsA, int bsB, int bsC, int bsBias) {
  __shared__ __align__(16) f16 As[64*40];
  __shared__ __align__(16) f16 Bs[128*40];
  int t = threadIdx.x;
  int m0 = blockIdx.x*64, n0 = blockIdx.y*128, z = blockIdx.z;
  A  += (size_t)z * bsA;
  BT += (size_t)z * bsB;
  if constexpr (MODE == 1) C += (size_t)z * bsC;
  else { Ch += (size_t)z * bsC; bias += (size_t)z * bsBias; }
  int lane = t & 63, wv = t >> 6, wm = wv >> 1, wn = wv & 1;
  int lr = lane & 15, lk = (lane >> 4) * 8;
  int arow = t >> 2, aseg = (t & 3) * 8;
  f32x4 acc[2][4] = {};
  for (int k0 = 0; k0 < K; k0 += 32) {
    __syncthreads();
    *(f16x8*)(&As[arow*40 + aseg]) = *(const f16x8*)(A + (size_t)(m0 + arow)*lda + k0 + aseg);
    *(f16x8*)(&Bs[arow*40 + aseg]) = *(const f16x8*)(BT + (size_t)(n0 + arow)*ldb + k0 + aseg);
    *(f16x8*)(&Bs[(64+arow)*40 + aseg]) = *(const f16x8*)(BT + (size_t)(n0 + 64 + arow)*ldb + k0 + aseg);
    __syncthreads();
    f16x8 af[2], bf[4];
    #pragma unroll
    for (int i = 0; i < 2; i++) af[i] = *(const f16x8*)(&As[(wm*32 + i*16 + lr)*40 + lk]);
    #pragma unroll
    for (int j = 0; j < 4; j++) bf[j] = *(const f16x8*)(&Bs[(wn*64 + j*16 + lr)*40 + lk]);
    #pragma unroll
    for (int i = 0; i < 2; i++)
      #pragma unroll
      for (int j = 0; j < 4; j++)
        acc[i][j] = __builtin_amdgcn_mfma_f32_16x16x32_f16(af[i], bf[j], acc[i][j], 0, 0, 0);
  }
  #pragma unroll
  for (int i = 0; i < 2; i++)
    #pragma unroll
    for (int j = 0; j < 4; j++)
      #pragma unroll
      for (int v = 0; v < 4; v++) {
        int r = m0 + wm*32 + i*16 + (lane >> 4)*4 + v;
        int cc = n0 + wn*64 + j*16 + lr;
        float val = acc[i][j][v];
        if constexpr (MODE == 1) {
          C[(size_t)r*N + cc] = val;
        } else {
          val += bias[cc];
          val = fmaxf(val, 0.f);
          Ch[(size_t)r*N + cc] = (f16)val;
        }
      }
}

// ---------------- GRU gates ----------------

__global__ __launch_bounds__(256) void k_gate(const float* __restrict__ gi,
    const float* __restrict__ gh, const float* __restrict__ bih, const float* __restrict__ bhh,
    const float* __restrict__ hOld, float* __restrict__ hNew, f16* __restrict__ xc16,
    f16* __restrict__ Agru) {
  int i = blockIdx.x*256 + threadIdx.x;
  int row = i >> 8, c = i & 255;
  const float* gir = gi + (size_t)row*768;
  const float* ghr = gh + (size_t)row*768;
  float ir  = gir[c]     + bih[c],     hr = ghr[c]     + bhh[c];
  float iz  = gir[256+c] + bih[256+c], hz = ghr[256+c] + bhh[256+c];
  float inn = gir[512+c] + bih[512+c], hn = ghr[512+c] + bhh[512+c];
  float r  = 1.f / (1.f + expf(-(ir + hr)));
  float zz = 1.f / (1.f + expf(-(iz + hz)));
  float nn = tanhf(inn + r*hn);
  float hv = (1.f - zz)*nn + zz*hOld[i];
  hNew[i] = hv;
  xc16[i] = (f16)hv;
  Agru[(size_t)row*512 + 256 + c] = (f16)hv;
}

// ---------------- head tail ----------------

__global__ __launch_bounds__(256) void k_mix(const f16* __restrict__ h2,
    const float* __restrict__ w3, const float* __restrict__ b3, float* __restrict__ mix) {
  int b = blockIdx.x, t = threadIdx.x;
  int wv = t >> 6, lane = t & 63;
  int rid = b*4 + wv;
  int m = rid >> 10, row = rid & 1023;
  const f16* hr = h2 + (size_t)(m*1024 + row)*DD;
  const float* w = w3 + m*DD;
  float s = 0.f;
  #pragma unroll
  for (int q = 0; q < 4; q++) { int d = lane + q*64; s += (float)hr[d] * w[d]; }
  #pragma unroll
  for (int o = 32; o; o >>= 1) s += __shfl_down(s, o, 64);
  if (lane == 0) mix[m*1024 + row] = s + b3[m];
}

__global__ __launch_bounds__(256) void k_out(const float* __restrict__ mix, float* __restrict__ out) {
  int i = blockIdx.x*256 + threadIdx.x;
  float v[10]; float mu = 0.f;
  #pragma unroll
  for (int m = 0; m < 10; m++) { v[m] = mix[m*1024 + i]; mu += v[m]; }
  mu *= 0.1f;
  float var = 0.f;
  #pragma unroll
  for (int m = 0; m < 10; m++) { float d = v[m] - mu; var += d*d; }
  var *= (1.f/9.f);
  out[i] = mu;
  out[1024 + i] = sqrtf(var + 1e-5f);
}

// ---------------- launch ----------------

extern "C" void kernel_launch(void* const* d_in, const int* in_sizes, int n_in,
                              void* d_out, int out_size, void* d_ws, size_t ws_size,
                              hipStream_t stream) {
  const float* x         = (const float*)d_in[0];
  const float* edge_attr = (const float*)d_in[1];
  const int*   edge_idx  = (const int*)  d_in[2];
  const float* lin_w     = (const float*)d_in[3];
  const float* lin_b     = (const float*)d_in[4];
  const float* bn_g      = (const float*)d_in[5];
  const float* bn_b      = (const float*)d_in[6];
  const float* nn_w1     = (const float*)d_in[7];
  const float* nn_b1     = (const float*)d_in[8];
  const float* nn_w2     = (const float*)d_in[9];
  const float* nn_b2     = (const float*)d_in[10];
  const float* root_w    = (const float*)d_in[11];
  const float* conv_b    = (const float*)d_in[12];
  const float* gru_wih   = (const float*)d_in[13];
  const float* gru_whh   = (const float*)d_in[14];
  const float* gru_bih   = (const float*)d_in[15];
  const float* gru_bhh   = (const float*)d_in[16];
  const float* mlp_w1    = (const float*)d_in[17];
  const float* mlp_b1    = (const float*)d_in[18];
  const float* mlp_w2    = (const float*)d_in[19];
  const float* mlp_b2    = (const float*)d_in[20];
  const float* mlp_w3    = (const float*)d_in[21];
  const float* mlp_b3    = (const float*)d_in[22];
  float* out = (float*)d_out;

  char* w = (char*)d_ws;
  size_t o = 0;
  auto nxt = [&](size_t b) -> size_t { size_t r = o; o += (b + 255) & ~(size_t)255; return r; };
  float* y      = (float*)(w + nxt(1048576));
  float* colsum = (float*)(w + nxt(1024));
  float* colsq  = (float*)(w + nxt(1024));
  float* xh     = (float*)(w + nxt(1048576));
  float* h      = (float*)(w + nxt(1048576));
  f16*   xc16   = (f16*)  (w + nxt(524288));
  float* hid    = (float*)(w + nxt(1048576));
  int*   cntAll = (int*)  (w + nxt(8192));
  int*   offAll = (int*)  (w + nxt(8192));
  int*   curAll = (int*)  (w + nxt(8192));
  float* denomB = (float*)(w + nxt(4096));
  int*   eordD  = (int*)  (w + nxt(8192));
  int*   eordS  = (int*)  (w + nxt(8192));
  int*   posArr = (int*)  (w + nxt(8192));
  f16*   BTb    = (f16*)  (w + nxt((size_t)NT*256*2));          // 17.0 MB
  f16*   T      = (f16*)  (w + nxt((size_t)1024*NT*2));         // 68.2 MB
  float* msgbuf = (float*)(w + nxt((size_t)EE*256*4));          // 2 MB
  f16*   Agru   = (f16*)  (w + nxt(1048576));                   // [1024][512] = [m | h]
  float* G      = (float*)(w + nxt((size_t)2*1024*768*4));      // gi, gh
  f16*   Wb     = (f16*)  (w + nxt(786432));                    // [2][768][256]
  f16*   w1T    = (f16*)  (w + nxt(1310720));
  f16*   w2T    = (f16*)  (w + nxt(1310720));
  f16*   h1     = (f16*)  (w + nxt(5242880));
  f16*   h2     = (f16*)  (w + nxt(5242880));
  float* mixb   = (float*)(w + nxt(40960));
  if (o > ws_size) return;

  hipMemsetAsync(colsum, 0, 2048, stream);   // colsum + colsq contiguous
  hipMemsetAsync(cntAll, 0, 8192, stream);

  k_embed_hidden<<<2048, 256, 0, stream>>>(x, lin_w, lin_b, edge_attr, nn_w1, nn_b1,
                                           y, colsum, colsq, hid);
  k_bnapply<<<1024, 256, 0, stream>>>(y, colsum, colsq, bn_g, bn_b, xh, xc16, Agru);
  k_cnt2 <<<16, 256, 0, stream>>>(edge_idx, cntAll);
  k_scan2<<<2, 1024, 0, stream>>>(cntAll, offAll, curAll, denomB);
  k_fill2<<<16, 256, 0, stream>>>(edge_idx, curAll, eordD, eordS, posArr);
  k_w2tr <<<dim3(256, 2), 256, 0, stream>>>(nn_w2, BTb);
  k_auxB <<<68, 256, 0, stream>>>(root_w, nn_b2, BTb);
  k_castall<<<1664, 256, 0, stream>>>(gru_wih, Wb, gru_whh, Wb + 196608,
                                      mlp_w1, w1T, mlp_w2, w2T);

  for (int it = 0; it < 3; it++) {
    const float* hOld = (it == 0) ? xh : h;
    k_gemm1<<<2112, 256, 0, stream>>>(xc16, BTb, T);
    k_msg  <<<1024, 256, 0, stream>>>(T, hid, cntAll, offAll, eordS, posArr, msgbuf);
    k_fin  <<<1024, 256, 0, stream>>>(msgbuf, cntAll, offAll, denomB, T, conv_b, Agru);
    k_gemm_sm<1><<<dim3(16, 6, 2), 256, 0, stream>>>(Agru, Wb, G,
        nullptr, nullptr, 256, 512, 256, 768, 256, 196608, 786432, 0);
    k_gate<<<1024, 256, 0, stream>>>(G, G + 786432, gru_bih, gru_bhh, hOld, h, xc16, Agru);
  }

  k_gemm_sm<3><<<dim3(16, 2, 10), 256, 0, stream>>>(Agru + 256, w1T, nullptr, h1, mlp_b1,
      256, 512, 256, 256, 0, 65536, 262144, 256);
  k_gemm_sm<3><<<dim3(16, 2, 10), 256, 0, stream>>>(h1, w2T, nullptr, h2, mlp_b2,
      256, 256, 256, 256, 262144, 65536, 262144, 256);
  k_mix<<<2560, 256, 0, stream>>>(h2, mlp_w3, mlp_b3, mixb);
  k_out<<<4, 256, 0, stream>>>(mixb, out);
}